// Round 3
// baseline (219.352 us; speedup 1.0000x reference)
//
#include <hip/hip_runtime.h>
#include <math.h>

#define I_N 64
#define Q_N 49
#define T_N 64
#define S_N 64
#define D_N 256

typedef __attribute__((ext_vector_type(8))) short short8;
typedef __attribute__((ext_vector_type(4))) float f32x4;
typedef unsigned short ushort_t;

__device__ __forceinline__ float waveReduceSum64(float v) {
    v += __shfl_xor(v, 1);
    v += __shfl_xor(v, 2);
    v += __shfl_xor(v, 4);
    v += __shfl_xor(v, 8);
    v += __shfl_xor(v, 16);
    v += __shfl_xor(v, 32);
    return v;
}

__device__ __forceinline__ ushort_t f2bf(float x) {
    unsigned u = __builtin_bit_cast(unsigned, x);
    unsigned r = (u + 0x7fffu + ((u >> 16) & 1u)) >> 16;
    return (ushort_t)r;
}
__device__ __forceinline__ float bf2f(ushort_t h) {
    unsigned u = ((unsigned)h) << 16;
    return __builtin_bit_cast(float, u);
}
__device__ __forceinline__ void split_bf16(float x, ushort_t& h, ushort_t& l) {
    h = f2bf(x);
    l = f2bf(x - bf2f(h));
}

// ---------- prep: normalize img query rows (pad q>=49 with zeros), split to bf16 hi/lo,
// ---------- and compute ||img_value|| per (i,q). grid = I_N*64, block = 256.
__global__ void prep_img(const float* __restrict__ q_in, const float* __restrict__ v_in,
                         ushort_t* __restrict__ qh, ushort_t* __restrict__ ql,
                         float* __restrict__ vnorm) {
    int row = blockIdx.x;             // i*64 + q
    int i = row >> 6, q = row & 63;
    int tid = threadIdx.x;
    float x = 0.0f, vv = 0.0f;
    if (q < Q_N) {
        size_t base = ((size_t)i * Q_N + q) * D_N + tid;
        x = q_in[base];
        vv = v_in[base];
    }
    __shared__ float ws[8];
    float s1 = waveReduceSum64(x * x);
    float s2 = waveReduceSum64(vv * vv);
    int wv = tid >> 6, ln = tid & 63;
    if (ln == 0) { ws[wv] = s1; ws[4 + wv] = s2; }
    __syncthreads();
    float n1 = sqrtf(ws[0] + ws[1] + ws[2] + ws[3]);
    float n2 = sqrtf(ws[4] + ws[5] + ws[6] + ws[7]);
    float xn = x / fmaxf(n1, 1e-12f);
    ushort_t h, l;
    split_bf16(xn, h, l);
    qh[(size_t)row * D_N + tid] = h;
    ql[(size_t)row * D_N + tid] = l;
    if (tid == 0) vnorm[row] = n2;    // 0 for padded rows
}

// ---------- prep: normalize text key rows, split. grid = T_N*64, block = 256.
__global__ void prep_txt(const float* __restrict__ k_in,
                         ushort_t* __restrict__ kh, ushort_t* __restrict__ kl) {
    int row = blockIdx.x;             // t*64 + s
    int tid = threadIdx.x;
    float x = k_in[(size_t)row * D_N + tid];
    __shared__ float ws[4];
    float s1 = waveReduceSum64(x * x);
    int wv = tid >> 6, ln = tid & 63;
    if (ln == 0) ws[wv] = s1;
    __syncthreads();
    float n1 = sqrtf(ws[0] + ws[1] + ws[2] + ws[3]);
    float xn = x / fmaxf(n1, 1e-12f);
    ushort_t h, l;
    split_bf16(xn, h, l);
    kh[(size_t)row * D_N + tid] = h;
    kl[(size_t)row * D_N + tid] = l;
}

// ---------- prep: transpose text value to [T][D][S] via LDS tile, split.
// grid = (T_N, 4), block = 256. blockIdx.y picks a 64-wide d-slab.
__global__ void prep_vt(const float* __restrict__ tv,
                        ushort_t* __restrict__ vth, ushort_t* __restrict__ vtl) {
    __shared__ float tile[64][65];
    int t = blockIdx.x;
    int d0 = blockIdx.y * 64;
    int tid = threadIdx.x;
    const float* src = tv + ((size_t)t << 14) + d0;   // rows [s][d0..d0+63]
    ushort_t* dh = vth + ((size_t)t << 14);
    ushort_t* dl = vtl + ((size_t)t << 14);
#pragma unroll
    for (int r = 0; r < 16; ++r) {
        int idx = r * 256 + tid;
        int s = idx >> 6, d = idx & 63;
        tile[s][d] = src[s * D_N + d];
    }
    __syncthreads();
#pragma unroll
    for (int r = 0; r < 16; ++r) {
        int idx = r * 256 + tid;
        int d = idx >> 6, s = idx & 63;
        float x = tile[s][d];
        ushort_t h, l;
        split_bf16(x, h, l);
        dh[(d0 + d) * 64 + s] = h;
        dl[(d0 + d) * 64 + s] = l;
    }
}

// ---------- prep: permuted img_value for vectorized epilogue loads ----------
// vP[i][w][lr][q][ni] = vimg[i][q][w*64 + ni*16 + lr]  (fp32, zero for q>=49)
// grid = I_N, block = 256, 64 outputs per thread.
__global__ void prep_vp(const float* __restrict__ vimg, float* __restrict__ vP) {
    int i = blockIdx.x;
    int tid = threadIdx.x;
    const float* src = vimg + (size_t)i * Q_N * D_N;
    float* dst = vP + ((size_t)i << 14);
#pragma unroll
    for (int r = 0; r < 64; ++r) {
        int o = r * 256 + tid;           // ((w*16+lr)*64 + q)*4 + ni
        int ni = o & 3;
        int q = (o >> 2) & 63;
        int lr = (o >> 8) & 15;
        int w = o >> 12;
        dst[o] = (q < Q_N) ? src[q * D_N + w * 64 + ni * 16 + lr] : 0.0f;
    }
}

// ---------- main: one block per (t,i) ----------
__launch_bounds__(256, 4)
__global__ void i2t_mfma(const ushort_t* __restrict__ qh, const ushort_t* __restrict__ ql,
                         const ushort_t* __restrict__ kh, const ushort_t* __restrict__ kl,
                         const ushort_t* __restrict__ vth, const ushort_t* __restrict__ vtl,
                         const float* __restrict__ vP,     // [I][4][16][64][4]
                         const float* __restrict__ vnorm,  // [I][64]
                         const int* __restrict__ tlen,
                         float* __restrict__ out)          // [I][T]
{
    __shared__ float As[64 * 65];                       // attn [s][q], fp32
    __shared__ __align__(16) ushort_t Ph[64 * 64];      // P hi, swizzled 128B rows
    __shared__ __align__(16) ushort_t Pl[64 * 64];      // P lo
    __shared__ float rinv[64];
    __shared__ float wsq[4][64], wdv[4][64];

    // XCD-grouped mapping: each XCD owns 8 consecutive t values for the whole dispatch,
    // so K[t]/Vt[t] stay L2-resident (8 t x 128KB = 1MB per XCD).
    const int bid = blockIdx.x;
    const int xcd = bid & 7;
    const int j = bid >> 3;
    const int t = (xcd << 3) | (j & 7);
    const int i = j >> 3;

    const int tid = threadIdx.x;
    const int lane = tid & 63;
    const int w = tid >> 6;        // wave 0..3
    const int lr = lane & 15;      // fragment row/col index
    const int lk = lane >> 4;      // fragment k-group (0..3)

    // ================= Phase 1: attn[s][q] = kn[t] . qn[i]^T  (split-bf16 MFMA) =========
    {
        const int m0 = (w >> 1) * 32;   // s-base of this wave
        const int n0 = (w & 1) * 32;    // q-base
        const ushort_t* khT = kh + ((size_t)t << 14);
        const ushort_t* klT = kl + ((size_t)t << 14);
        const ushort_t* qhI = qh + ((size_t)i << 14);
        const ushort_t* qlI = ql + ((size_t)i << 14);

        f32x4 acc[2][2];
#pragma unroll
        for (int a = 0; a < 2; ++a)
#pragma unroll
            for (int b = 0; b < 2; ++b) acc[a][b] = (f32x4){0.f, 0.f, 0.f, 0.f};

#pragma unroll
        for (int k0 = 0; k0 < 256; k0 += 32) {
            short8 aH[2], aL[2], bH[2], bL[2];
            const int dd = k0 + lk * 8;
#pragma unroll
            for (int mi = 0; mi < 2; ++mi) {
                int s = m0 + mi * 16 + lr;
                aH[mi] = *(const short8*)(khT + s * D_N + dd);
                aL[mi] = *(const short8*)(klT + s * D_N + dd);
            }
#pragma unroll
            for (int ni = 0; ni < 2; ++ni) {
                int q = n0 + ni * 16 + lr;
                bH[ni] = *(const short8*)(qhI + q * D_N + dd);
                bL[ni] = *(const short8*)(qlI + q * D_N + dd);
            }
#pragma unroll
            for (int mi = 0; mi < 2; ++mi)
#pragma unroll
                for (int ni = 0; ni < 2; ++ni) {
                    acc[mi][ni] = __builtin_amdgcn_mfma_f32_16x16x32_bf16(aH[mi], bH[ni], acc[mi][ni], 0, 0, 0);
                    acc[mi][ni] = __builtin_amdgcn_mfma_f32_16x16x32_bf16(aH[mi], bL[ni], acc[mi][ni], 0, 0, 0);
                    acc[mi][ni] = __builtin_amdgcn_mfma_f32_16x16x32_bf16(aL[mi], bH[ni], acc[mi][ni], 0, 0, 0);
                }
        }
        // LeakyReLU + scatter to As[s][q]
#pragma unroll
        for (int mi = 0; mi < 2; ++mi)
#pragma unroll
            for (int ni = 0; ni < 2; ++ni)
#pragma unroll
                for (int r = 0; r < 4; ++r) {
                    int s = m0 + mi * 16 + lk * 4 + r;
                    int q = n0 + ni * 16 + lr;
                    float v = acc[mi][ni][r];
                    v = (v > 0.0f) ? v : 0.1f * v;
                    As[s * 65 + q] = v;
                }
    }
    __syncthreads();

    // ================= Phase 2a: per-s l2norm over q =================
    {
        int s = tid >> 2, part = tid & 3;
        float ss = 0.0f;
#pragma unroll
        for (int q0 = 0; q0 < 64; q0 += 4) {
            float v = As[s * 65 + q0 + part];
            ss += v * v;
        }
        ss += __shfl_xor(ss, 1);
        ss += __shfl_xor(ss, 2);
        if (part == 0) rinv[s] = 1.0f / fmaxf(sqrtf(ss), 1e-12f);
    }
    __syncthreads();

    // ================= Phase 2b: masked softmax over s + focal, write P hi/lo =========
    const int len = tlen[t];
    {
        const float thr = 1.0f / (float)len;
        int q = tid >> 2, part = tid & 3;
        float logit[16];
        float m = -INFINITY;
#pragma unroll
        for (int k = 0; k < 16; ++k) {
            int s = part * 16 + k;
            float lg = (s < len) ? 10.0f * As[s * 65 + q] * rinv[s] : -INFINITY;
            logit[k] = lg;
            m = fmaxf(m, lg);
        }
        m = fmaxf(m, __shfl_xor(m, 1));
        m = fmaxf(m, __shfl_xor(m, 2));
        float p[16];
        float sum = 0.0f;
#pragma unroll
        for (int k = 0; k < 16; ++k) {
            int s = part * 16 + k;
            float e = (s < len) ? __expf(logit[k] - m) : 0.0f;
            p[k] = e;
            sum += e;
        }
        sum += __shfl_xor(sum, 1);
        sum += __shfl_xor(sum, 2);
        float inv = 1.0f / sum;
        float sk = 0.0f;
#pragma unroll
        for (int k = 0; k < 16; ++k) {
            p[k] *= inv;
            if (p[k] > thr) sk += p[k];
        }
        sk += __shfl_xor(sk, 1);
        sk += __shfl_xor(sk, 2);
        float iv2 = 1.0f / sk;

        ushort_t hh[16], ll[16];
#pragma unroll
        for (int k = 0; k < 16; ++k) {
            float pv = (p[k] > thr) ? p[k] * iv2 : 0.0f;
            if (q >= Q_N) pv = 0.0f;   // padded query rows -> zero weights
            split_bf16(pv, hh[k], ll[k]);
        }
        // swizzled 16B-chunk writes: chunk c of row q lives at (c ^ (q&7))
        int c0 = (2 * part) ^ (q & 7);
        int c1 = (2 * part + 1) ^ (q & 7);
        char* baseH = (char*)Ph + q * 128;
        char* baseL = (char*)Pl + q * 128;
        short8 v0, v1;
#pragma unroll
        for (int k = 0; k < 8; ++k) { v0[k] = (short)hh[k]; v1[k] = (short)hh[k + 8]; }
        *(short8*)(baseH + (c0 << 4)) = v0;
        *(short8*)(baseH + (c1 << 4)) = v1;
#pragma unroll
        for (int k = 0; k < 8; ++k) { v0[k] = (short)ll[k]; v1[k] = (short)ll[k + 8]; }
        *(short8*)(baseL + (c0 << 4)) = v0;
        *(short8*)(baseL + (c1 << 4)) = v1;
    }
    __syncthreads();

    // ================= Phase 3: wei[q][d] = P[q][s] * Vt[d][s]  (split-bf16 MFMA) ======
    f32x4 acc2[4][4];
#pragma unroll
    for (int a = 0; a < 4; ++a)
#pragma unroll
        for (int b = 0; b < 4; ++b) acc2[a][b] = (f32x4){0.f, 0.f, 0.f, 0.f};
    {
        const ushort_t* vhT = vth + ((size_t)t << 14);
        const ushort_t* vlT = vtl + ((size_t)t << 14);
#pragma unroll
        for (int k0 = 0; k0 < 64; k0 += 32) {
            short8 pah[4], pal[4];
#pragma unroll
            for (int mi = 0; mi < 4; ++mi) {
                int q = mi * 16 + lr;
                int c = (k0 >> 3) + lk;
                int off = q * 128 + ((c ^ (q & 7)) << 4);
                pah[mi] = *(const short8*)((const char*)Ph + off);
                pal[mi] = *(const short8*)((const char*)Pl + off);
            }
#pragma unroll
            for (int ni = 0; ni < 4; ++ni) {
                int d = w * 64 + ni * 16 + lr;
                int go = d * 64 + k0 + lk * 8;
                short8 bh = *(const short8*)(vhT + go);
                short8 bl = *(const short8*)(vlT + go);
#pragma unroll
                for (int mi = 0; mi < 4; ++mi) {
                    acc2[mi][ni] = __builtin_amdgcn_mfma_f32_16x16x32_bf16(pah[mi], bh, acc2[mi][ni], 0, 0, 0);
                    acc2[mi][ni] = __builtin_amdgcn_mfma_f32_16x16x32_bf16(pal[mi], bh, acc2[mi][ni], 0, 0, 0);
                    acc2[mi][ni] = __builtin_amdgcn_mfma_f32_16x16x32_bf16(pah[mi], bl, acc2[mi][ni], 0, 0, 0);
                }
            }
        }
    }

    // ================= Epilogue: fused ||wei|| and wei.v (vector loads), reduce over d ==
    {
        const float* vPb = vP + ((((size_t)i * 4 + w) * 16 + lr) << 8);
#pragma unroll
        for (int mi = 0; mi < 4; ++mi)
#pragma unroll
            for (int r = 0; r < 4; ++r) {
                int q = mi * 16 + lk * 4 + r;
                f32x4 vv = *(const f32x4*)(vPb + q * 4);
                float s2 = 0.0f, dv = 0.0f;
#pragma unroll
                for (int ni = 0; ni < 4; ++ni) {
                    float wv = acc2[mi][ni][r];
                    s2 += wv * wv;
                    dv += wv * vv[ni];
                }
#pragma unroll
                for (int mask = 1; mask <= 8; mask <<= 1) {
                    s2 += __shfl_xor(s2, mask);
                    dv += __shfl_xor(dv, mask);
                }
                if (lr == 0) { wsq[w][q] = s2; wdv[w][q] = dv; }
            }
    }
    __syncthreads();
    if (tid < 64) {
        int q = tid;
        float s2 = wsq[0][q] + wsq[1][q] + wsq[2][q] + wsq[3][q];
        float dv = wdv[0][q] + wdv[1][q] + wdv[2][q] + wdv[3][q];
        float sim = 0.0f;
        if (q < Q_N) {
            float wn = sqrtf(s2);
            float w12 = dv / fmaxf(wn, 1e-12f);
            float wnn = wn / fmaxf(wn, 1e-12f);
            float denom = fmaxf(vnorm[i * 64 + q] * wnn, 1e-8f);
            sim = w12 / denom;
        }
        sim = waveReduceSum64(sim);
        if (tid == 0) out[(size_t)i * T_N + t] = sim * (1.0f / (float)Q_N);
    }
}

extern "C" void kernel_launch(void* const* d_in, const int* in_sizes, int n_in,
                              void* d_out, int out_size, void* d_ws, size_t ws_size,
                              hipStream_t stream) {
    const float* img_query = (const float*)d_in[0];  // [I,49,D]
    const float* img_value = (const float*)d_in[1];  // [I,49,D]
    const float* text_key  = (const float*)d_in[2];  // [T,64,D]
    const float* text_val  = (const float*)d_in[3];  // [T,64,D]
    const int*   text_len  = (const int*)d_in[4];    // [T]
    float* out = (float*)d_out;

    const size_t NPAD = (size_t)64 * 64 * 256;       // 1,048,576 elements
    ushort_t* qh  = (ushort_t*)d_ws;
    ushort_t* ql  = qh + NPAD;
    ushort_t* kh  = ql + NPAD;
    ushort_t* kl  = kh + NPAD;
    ushort_t* vth = kl + NPAD;
    ushort_t* vtl = vth + NPAD;
    float* vnorm  = (float*)(vtl + NPAD);            // [I*64]
    float* vP     = vnorm + I_N * 64;                // [I][4][16][64][4] = 4 MB

    prep_img<<<I_N * 64, 256, 0, stream>>>(img_query, img_value, qh, ql, vnorm);
    prep_txt<<<T_N * 64, 256, 0, stream>>>(text_key, kh, kl);
    prep_vt<<<dim3(T_N, 4), 256, 0, stream>>>(text_val, vth, vtl);
    prep_vp<<<I_N, 256, 0, stream>>>(img_value, vP);

    i2t_mfma<<<T_N * I_N, 256, 0, stream>>>(qh, ql, kh, kl, vth, vtl,
                                            vP, vnorm, text_len, out);
}

// Round 4
// 203.929 us; speedup vs baseline: 1.0756x; 1.0756x over previous
//
#include <hip/hip_runtime.h>
#include <math.h>

#define I_N 64
#define Q_N 49
#define T_N 64
#define S_N 64
#define D_N 256

typedef __attribute__((ext_vector_type(8))) short short8;
typedef __attribute__((ext_vector_type(4))) float f32x4;
typedef __attribute__((ext_vector_type(2))) float f32x2;
typedef unsigned short ushort_t;

__device__ __forceinline__ float waveReduceSum64(float v) {
    v += __shfl_xor(v, 1);
    v += __shfl_xor(v, 2);
    v += __shfl_xor(v, 4);
    v += __shfl_xor(v, 8);
    v += __shfl_xor(v, 16);
    v += __shfl_xor(v, 32);
    return v;
}

__device__ __forceinline__ ushort_t f2bf(float x) {
    unsigned u = __builtin_bit_cast(unsigned, x);
    unsigned r = (u + 0x7fffu + ((u >> 16) & 1u)) >> 16;
    return (ushort_t)r;
}
__device__ __forceinline__ float bf2f(ushort_t h) {
    unsigned u = ((unsigned)h) << 16;
    return __builtin_bit_cast(float, u);
}
__device__ __forceinline__ void split_bf16(float x, ushort_t& h, ushort_t& l) {
    h = f2bf(x);
    l = f2bf(x - bf2f(h));
}

// async global->LDS, 16B per lane; LDS base must be wave-uniform
__device__ __forceinline__ void gload16(const void* g, void* l) {
    __builtin_amdgcn_global_load_lds(
        (const __attribute__((address_space(1))) unsigned int*)g,
        (__attribute__((address_space(3))) unsigned int*)l, 16, 0, 0);
}

// ---------- prep: normalize img query rows (pad q>=49 with zeros), split, plain layout;
// ---------- compute ||img_value||. grid = I_N*64, block = 256.
__global__ void prep_img(const float* __restrict__ q_in, const float* __restrict__ v_in,
                         ushort_t* __restrict__ qh, ushort_t* __restrict__ ql,
                         float* __restrict__ vnorm) {
    int row = blockIdx.x;             // i*64 + q
    int i = row >> 6, q = row & 63;
    int tid = threadIdx.x;
    float x = 0.0f, vv = 0.0f;
    if (q < Q_N) {
        size_t base = ((size_t)i * Q_N + q) * D_N + tid;
        x = q_in[base];
        vv = v_in[base];
    }
    __shared__ float ws[8];
    float s1 = waveReduceSum64(x * x);
    float s2 = waveReduceSum64(vv * vv);
    int wv = tid >> 6, ln = tid & 63;
    if (ln == 0) { ws[wv] = s1; ws[4 + wv] = s2; }
    __syncthreads();
    float n1 = sqrtf(ws[0] + ws[1] + ws[2] + ws[3]);
    float n2 = sqrtf(ws[4] + ws[5] + ws[6] + ws[7]);
    float xn = x / fmaxf(n1, 1e-12f);
    ushort_t h, l;
    split_bf16(xn, h, l);
    qh[(size_t)row * D_N + tid] = h;
    ql[(size_t)row * D_N + tid] = l;
    if (tid == 0) vnorm[row] = n2;
}

// ---------- prep: normalize text key rows, split, SWIZZLED row layout ----------
// within row s, 16B chunk c (=d>>3) is stored at chunk position c ^ (s&7).
__global__ void prep_txt(const float* __restrict__ k_in,
                         ushort_t* __restrict__ khs, ushort_t* __restrict__ kls) {
    int row = blockIdx.x;             // t*64 + s
    int s = row & 63;
    int tid = threadIdx.x;            // d
    float x = k_in[(size_t)row * D_N + tid];
    __shared__ float ws[4];
    float s1 = waveReduceSum64(x * x);
    int wv = tid >> 6, ln = tid & 63;
    if (ln == 0) ws[wv] = s1;
    __syncthreads();
    float n1 = sqrtf(ws[0] + ws[1] + ws[2] + ws[3]);
    float xn = x / fmaxf(n1, 1e-12f);
    ushort_t h, l;
    split_bf16(xn, h, l);
    int c = tid >> 3, e = tid & 7;
    int o = ((c ^ (s & 7)) << 3) + e;
    khs[(size_t)row * D_N + o] = h;
    kls[(size_t)row * D_N + o] = l;
}

// ---------- prep: transpose text value to [T][D][S] via LDS tile, split, plain layout.
// grid = (T_N, 4), block = 256.
__global__ void prep_vt(const float* __restrict__ tv,
                        ushort_t* __restrict__ vth, ushort_t* __restrict__ vtl) {
    __shared__ float tile[64][65];
    int t = blockIdx.x;
    int d0 = blockIdx.y * 64;
    int tid = threadIdx.x;
    const float* src = tv + ((size_t)t << 14) + d0;
    ushort_t* dh = vth + ((size_t)t << 14);
    ushort_t* dl = vtl + ((size_t)t << 14);
#pragma unroll
    for (int r = 0; r < 16; ++r) {
        int idx = r * 256 + tid;
        int s = idx >> 6, d = idx & 63;
        tile[s][d] = src[s * D_N + d];
    }
    __syncthreads();
#pragma unroll
    for (int r = 0; r < 16; ++r) {
        int idx = r * 256 + tid;
        int d = idx >> 6, s = idx & 63;
        float x = tile[s][d];
        ushort_t h, l;
        split_bf16(x, h, l);
        dh[(d0 + d) * 64 + s] = h;
        dl[(d0 + d) * 64 + s] = l;
    }
}

// ---------- prep: permuted img_value for vectorized epilogue (8-wave layout) ----------
// vP[i][w8][lr16][q64][ni2] = vimg[i][q][w*32 + ni*16 + lr]   (0 for q>=49)
__global__ void prep_vp(const float* __restrict__ vimg, float* __restrict__ vP) {
    int i = blockIdx.x;
    int tid = threadIdx.x;
    const float* src = vimg + (size_t)i * Q_N * D_N;
    float* dst = vP + ((size_t)i << 14);       // 16384 floats per image
#pragma unroll
    for (int r = 0; r < 64; ++r) {
        int o = r * 256 + tid;
        int ni = o & 1;
        int q = (o >> 1) & 63;
        int lr = (o >> 7) & 15;
        int w = o >> 11;
        int d = w * 32 + ni * 16 + lr;
        dst[o] = (q < Q_N) ? src[q * D_N + d] : 0.0f;
    }
}

// ---------- main: one 512-thread block per (t,i) ----------
__launch_bounds__(512, 4)
__global__ void i2t_mfma(const ushort_t* __restrict__ khs, const ushort_t* __restrict__ kls,
                         const ushort_t* __restrict__ qh, const ushort_t* __restrict__ ql,
                         const ushort_t* __restrict__ vth, const ushort_t* __restrict__ vtl,
                         const float* __restrict__ vP,
                         const float* __restrict__ vnorm,
                         const int* __restrict__ tlen,
                         float* __restrict__ out)
{
    // 64KB region: phase1 = K hi(32K)+lo(32K); after phase1 overlaid with
    // As fp32 [64][65] @0 (16640B), Ph @20480 (8K), Pl @28672 (8K).
    __shared__ __align__(16) unsigned char RK[65536];
    __shared__ float wsq[8][64], wdv[8][64];
    __shared__ float rinv[64];

    const int bid = blockIdx.x;
    const int xcd = bid & 7;
    const int j = bid >> 3;
    const int t = (xcd << 3) | (j & 7);   // each XCD owns 8 t values -> K/Vt L2-resident
    const int i = j >> 3;

    const int tid = threadIdx.x;
    const int lane = tid & 63;
    const int w = tid >> 6;        // wave 0..7
    const int lr = lane & 15;
    const int lk = lane >> 4;

    // ---- stage K (pre-swizzled global -> linear LDS copy) ----
    {
        const char* gH = (const char*)(khs + ((size_t)t << 14));
        const char* gL = (const char*)(kls + ((size_t)t << 14));
#pragma unroll
        for (int r = 0; r < 4; ++r) {
            int off = w * 4096 + r * 1024;            // wave-uniform
            gload16(gH + off + lane * 16, RK + off);
            gload16(gL + off + lane * 16, RK + 32768 + off);
        }
    }
    __syncthreads();

    // ================= Phase 1: attn[s][q] = K.Q^T, wave = 32s x 16q =================
    const int wsr = (w >> 2) * 32;    // s-base
    const int wq  = (w & 3) * 16;     // q-base
    f32x4 acc[2];
    acc[0] = (f32x4){0.f, 0.f, 0.f, 0.f};
    acc[1] = (f32x4){0.f, 0.f, 0.f, 0.f};
    {
        const ushort_t* qhI = qh + ((size_t)i << 14);
        const ushort_t* qlI = ql + ((size_t)i << 14);
        const ushort_t* KH = (const ushort_t*)RK;
        const ushort_t* KL = (const ushort_t*)(RK + 32768);
#pragma unroll
        for (int k8 = 0; k8 < 8; ++k8) {
            const int dd = k8 * 32 + lk * 8;
            const int c = k8 * 4 + lk;               // 16B chunk index in row
            short8 aH[2], aL[2];
#pragma unroll
            for (int mi = 0; mi < 2; ++mi) {
                int s = wsr + mi * 16 + lr;
                int o = s * 256 + ((c ^ (s & 7)) << 3);
                aH[mi] = *(const short8*)(KH + o);
                aL[mi] = *(const short8*)(KL + o);
            }
            int q = wq + lr;
            short8 bH = *(const short8*)(qhI + q * 256 + dd);
            short8 bL = *(const short8*)(qlI + q * 256 + dd);
#pragma unroll
            for (int mi = 0; mi < 2; ++mi) {
                acc[mi] = __builtin_amdgcn_mfma_f32_16x16x32_bf16(aH[mi], bH, acc[mi], 0, 0, 0);
                acc[mi] = __builtin_amdgcn_mfma_f32_16x16x32_bf16(aH[mi], bL, acc[mi], 0, 0, 0);
                acc[mi] = __builtin_amdgcn_mfma_f32_16x16x32_bf16(aL[mi], bH, acc[mi], 0, 0, 0);
            }
        }
    }
    __syncthreads();    // all K LDS reads done -> region reusable

    // LeakyReLU + As overlay (region K is dead)
    {
        float* As = (float*)RK;
#pragma unroll
        for (int mi = 0; mi < 2; ++mi)
#pragma unroll
            for (int r = 0; r < 4; ++r) {
                int s = wsr + mi * 16 + lk * 4 + r;
                int q = wq + lr;
                float v = acc[mi][r];
                v = (v > 0.0f) ? v : 0.1f * v;
                As[s * 65 + q] = v;
            }
    }
    __syncthreads();

    // ================= Phase 2a: per-s l2norm over q (512 threads) =================
    {
        const float* As = (const float*)RK;
        int s = tid >> 3, part = tid & 7;
        float ss = 0.0f;
#pragma unroll
        for (int q0 = 0; q0 < 64; q0 += 8) {
            float v = As[s * 65 + q0 + part];
            ss += v * v;
        }
        ss += __shfl_xor(ss, 1);
        ss += __shfl_xor(ss, 2);
        ss += __shfl_xor(ss, 4);
        if (part == 0) rinv[s] = 1.0f / fmaxf(sqrtf(ss), 1e-12f);
    }
    __syncthreads();

    // ================= Phase 2b: masked softmax + focal, write swizzled P ==========
    const int len = tlen[t];
    {
        const float* As = (const float*)RK;
        ushort_t* Ph = (ushort_t*)(RK + 20480);
        ushort_t* Pl = (ushort_t*)(RK + 28672);
        const float thr = 1.0f / (float)len;
        int q = tid >> 3, part = tid & 7;      // part handles s in [part*8, part*8+8)
        float logit[8];
        float m = -INFINITY;
#pragma unroll
        for (int k = 0; k < 8; ++k) {
            int s = part * 8 + k;
            float lg = (s < len) ? 10.0f * As[s * 65 + q] * rinv[s] : -INFINITY;
            logit[k] = lg;
            m = fmaxf(m, lg);
        }
        m = fmaxf(m, __shfl_xor(m, 1));
        m = fmaxf(m, __shfl_xor(m, 2));
        m = fmaxf(m, __shfl_xor(m, 4));
        float p[8];
        float sum = 0.0f;
#pragma unroll
        for (int k = 0; k < 8; ++k) {
            int s = part * 8 + k;
            float e = (s < len) ? __expf(logit[k] - m) : 0.0f;
            p[k] = e;
            sum += e;
        }
        sum += __shfl_xor(sum, 1);
        sum += __shfl_xor(sum, 2);
        sum += __shfl_xor(sum, 4);
        float inv = 1.0f / sum;
        float sk = 0.0f;
#pragma unroll
        for (int k = 0; k < 8; ++k) {
            p[k] *= inv;
            if (p[k] > thr) sk += p[k];
        }
        sk += __shfl_xor(sk, 1);
        sk += __shfl_xor(sk, 2);
        sk += __shfl_xor(sk, 4);
        float iv2 = 1.0f / sk;

        short8 vh, vl;
#pragma unroll
        for (int k = 0; k < 8; ++k) {
            float pv = (p[k] > thr) ? p[k] * iv2 : 0.0f;
            if (q >= Q_N) pv = 0.0f;
            ushort_t hh, ll;
            split_bf16(pv, hh, ll);
            vh[k] = (short)hh;
            vl[k] = (short)ll;
        }
        int o = q * 64 + ((part ^ (q & 7)) << 3);    // ushort units, swizzled chunk
        *(short8*)(Ph + o) = vh;
        *(short8*)(Pl + o) = vl;
    }
    __syncthreads();

    // ================= Phase 3: wei[q][d] = P[q][s]*Vt[d][s]; wave = 64q x 32d ======
    f32x4 acc2[4][2];
#pragma unroll
    for (int a = 0; a < 4; ++a)
#pragma unroll
        for (int b = 0; b < 2; ++b) acc2[a][b] = (f32x4){0.f, 0.f, 0.f, 0.f};
    {
        const ushort_t* vhT = vth + ((size_t)t << 14);
        const ushort_t* vlT = vtl + ((size_t)t << 14);
        const ushort_t* PH = (const ushort_t*)(RK + 20480);
        const ushort_t* PL = (const ushort_t*)(RK + 28672);
#pragma unroll
        for (int k0 = 0; k0 < 64; k0 += 32) {
            short8 pah[4], pal[4];
#pragma unroll
            for (int mi = 0; mi < 4; ++mi) {
                int q = mi * 16 + lr;
                int c = (k0 >> 3) + lk;
                int o = q * 64 + ((c ^ (q & 7)) << 3);
                pah[mi] = *(const short8*)(PH + o);
                pal[mi] = *(const short8*)(PL + o);
            }
#pragma unroll
            for (int ni = 0; ni < 2; ++ni) {
                int d = w * 32 + ni * 16 + lr;
                int go = d * 64 + k0 + lk * 8;
                short8 bh = *(const short8*)(vhT + go);
                short8 bl = *(const short8*)(vlT + go);
#pragma unroll
                for (int mi = 0; mi < 4; ++mi) {
                    acc2[mi][ni] = __builtin_amdgcn_mfma_f32_16x16x32_bf16(pah[mi], bh, acc2[mi][ni], 0, 0, 0);
                    acc2[mi][ni] = __builtin_amdgcn_mfma_f32_16x16x32_bf16(pal[mi], bh, acc2[mi][ni], 0, 0, 0);
                    acc2[mi][ni] = __builtin_amdgcn_mfma_f32_16x16x32_bf16(pah[mi], bl, acc2[mi][ni], 0, 0, 0);
                }
            }
        }
    }

    // ================= Epilogue: fused ||wei|| and wei.v, reduce over d =============
    {
        const float* vPb = vP + ((((size_t)i * 8 + w) * 16 + lr) << 7);
#pragma unroll
        for (int mi = 0; mi < 4; ++mi)
#pragma unroll
            for (int r = 0; r < 4; ++r) {
                int q = mi * 16 + lk * 4 + r;
                f32x2 vv = *(const f32x2*)(vPb + q * 2);
                float s2 = 0.0f, dv = 0.0f;
#pragma unroll
                for (int ni = 0; ni < 2; ++ni) {
                    float wv = acc2[mi][ni][r];
                    s2 += wv * wv;
                    dv += wv * vv[ni];
                }
#pragma unroll
                for (int mask = 1; mask <= 8; mask <<= 1) {
                    s2 += __shfl_xor(s2, mask);
                    dv += __shfl_xor(dv, mask);
                }
                if (lr == 0) { wsq[w][q] = s2; wdv[w][q] = dv; }
            }
    }
    __syncthreads();
    if (tid < 64) {
        int q = tid;
        float s2 = 0.0f, dv = 0.0f;
#pragma unroll
        for (int ww = 0; ww < 8; ++ww) { s2 += wsq[ww][q]; dv += wdv[ww][q]; }
        float sim = 0.0f;
        if (q < Q_N) {
            float wn = sqrtf(s2);
            float w12 = dv / fmaxf(wn, 1e-12f);
            float wnn = wn / fmaxf(wn, 1e-12f);
            float denom = fmaxf(vnorm[i * 64 + q] * wnn, 1e-8f);
            sim = w12 / denom;
        }
        sim = waveReduceSum64(sim);
        if (tid == 0) out[(size_t)i * T_N + t] = sim * (1.0f / (float)Q_N);
    }
}

extern "C" void kernel_launch(void* const* d_in, const int* in_sizes, int n_in,
                              void* d_out, int out_size, void* d_ws, size_t ws_size,
                              hipStream_t stream) {
    const float* img_query = (const float*)d_in[0];  // [I,49,D]
    const float* img_value = (const float*)d_in[1];  // [I,49,D]
    const float* text_key  = (const float*)d_in[2];  // [T,64,D]
    const float* text_val  = (const float*)d_in[3];  // [T,64,D]
    const int*   text_len  = (const int*)d_in[4];    // [T]
    float* out = (float*)d_out;

    const size_t NPAD = (size_t)64 * 64 * 256;       // 1,048,576 elements
    ushort_t* qh  = (ushort_t*)d_ws;
    ushort_t* ql  = qh + NPAD;
    ushort_t* khs = ql + NPAD;
    ushort_t* kls = khs + NPAD;
    ushort_t* vth = kls + NPAD;
    ushort_t* vtl = vth + NPAD;
    float* vnorm  = (float*)(vtl + NPAD);            // [I*64]
    float* vP     = vnorm + I_N * 64;                // [I][8][16][64][2] = 4 MB

    prep_img<<<I_N * 64, 256, 0, stream>>>(img_query, img_value, qh, ql, vnorm);
    prep_txt<<<T_N * 64, 256, 0, stream>>>(text_key, khs, kls);
    prep_vt<<<dim3(T_N, 4), 256, 0, stream>>>(text_val, vth, vtl);
    prep_vp<<<I_N, 256, 0, stream>>>(img_value, vP);

    i2t_mfma<<<T_N * I_N, 512, 0, stream>>>(khs, kls, qh, ql, vth, vtl,
                                            vP, vnorm, text_len, out);
}

// Round 5
// 151.678 us; speedup vs baseline: 1.4462x; 1.3445x over previous
//
#include <hip/hip_runtime.h>
#include <math.h>

#define I_N 64
#define Q_N 49
#define T_N 64
#define S_N 64
#define D_N 256

typedef __attribute__((ext_vector_type(8))) short short8;
typedef __attribute__((ext_vector_type(4))) float f32x4;
typedef __attribute__((ext_vector_type(2))) float f32x2;
typedef unsigned short ushort_t;

__device__ __forceinline__ float waveReduceSum64(float v) {
    v += __shfl_xor(v, 1);
    v += __shfl_xor(v, 2);
    v += __shfl_xor(v, 4);
    v += __shfl_xor(v, 8);
    v += __shfl_xor(v, 16);
    v += __shfl_xor(v, 32);
    return v;
}

__device__ __forceinline__ ushort_t f2bf(float x) {
    unsigned u = __builtin_bit_cast(unsigned, x);
    unsigned r = (u + 0x7fffu + ((u >> 16) & 1u)) >> 16;
    return (ushort_t)r;
}
__device__ __forceinline__ float bf2f(ushort_t h) {
    unsigned u = ((unsigned)h) << 16;
    return __builtin_bit_cast(float, u);
}
__device__ __forceinline__ void split_bf16(float x, ushort_t& h, ushort_t& l) {
    h = f2bf(x);
    l = f2bf(x - bf2f(h));
}

// async global->LDS, 16B per lane; LDS base must be wave-uniform
__device__ __forceinline__ void gload16(const void* g, void* l) {
    __builtin_amdgcn_global_load_lds(
        (const __attribute__((address_space(1))) unsigned int*)g,
        (__attribute__((address_space(3))) unsigned int*)l, 16, 0, 0);
}

// ---------- prep: normalize img query rows, split, FRAGMENT-MAJOR layout ----------
// Qf[i][wqg][k8][lane][e]: q = wqg*16 + (lane&15), d = k8*32 + (lane>>4)*8 + e.
// Also compute ||img_value||. grid = I_N*64, block = 256.
__global__ void prep_img(const float* __restrict__ q_in, const float* __restrict__ v_in,
                         ushort_t* __restrict__ qfh, ushort_t* __restrict__ qfl,
                         float* __restrict__ vnorm) {
    int row = blockIdx.x;             // i*64 + q
    int i = row >> 6, q = row & 63;
    int tid = threadIdx.x;            // d
    float x = 0.0f, vv = 0.0f;
    if (q < Q_N) {
        size_t base = ((size_t)i * Q_N + q) * D_N + tid;
        x = q_in[base];
        vv = v_in[base];
    }
    __shared__ float ws[8];
    float s1 = waveReduceSum64(x * x);
    float s2 = waveReduceSum64(vv * vv);
    int wv = tid >> 6, ln = tid & 63;
    if (ln == 0) { ws[wv] = s1; ws[4 + wv] = s2; }
    __syncthreads();
    float n1 = sqrtf(ws[0] + ws[1] + ws[2] + ws[3]);
    float n2 = sqrtf(ws[4] + ws[5] + ws[6] + ws[7]);
    float xn = x / fmaxf(n1, 1e-12f);
    ushort_t h, l;
    split_bf16(xn, h, l);
    int wqg = q >> 4, lr = q & 15;
    int k8 = tid >> 5, lk = (tid >> 3) & 3, e = tid & 7;
    size_t off = ((size_t)i << 14) + (wqg << 12) + (k8 << 9) + lk * 128 + lr * 8 + e;
    qfh[off] = h;
    qfl[off] = l;
    if (tid == 0) vnorm[row] = n2;
}

// ---------- prep: normalize text key rows, split, SWIZZLED row layout ----------
// within row s, 16B chunk c (=d>>3) is stored at chunk position c ^ (s&7).
__global__ void prep_txt(const float* __restrict__ k_in,
                         ushort_t* __restrict__ khs, ushort_t* __restrict__ kls) {
    int row = blockIdx.x;             // t*64 + s
    int s = row & 63;
    int tid = threadIdx.x;            // d
    float x = k_in[(size_t)row * D_N + tid];
    __shared__ float ws[4];
    float s1 = waveReduceSum64(x * x);
    int wv = tid >> 6, ln = tid & 63;
    if (ln == 0) ws[wv] = s1;
    __syncthreads();
    float n1 = sqrtf(ws[0] + ws[1] + ws[2] + ws[3]);
    float xn = x / fmaxf(n1, 1e-12f);
    ushort_t h, l;
    split_bf16(xn, h, l);
    int c = tid >> 3, e = tid & 7;
    int o = ((c ^ (s & 7)) << 3) + e;
    khs[(size_t)row * D_N + o] = h;
    kls[(size_t)row * D_N + o] = l;
}

// ---------- prep: text value -> FRAGMENT-MAJOR transposed layout ----------
// Vf[t][w][k0g][ni][lane][e]: d = w*32 + ni*16 + (lane&15), s = k0g*32 + (lane>>4)*8 + e.
// grid = (T_N, 4), block = 256.
__global__ void prep_vt(const float* __restrict__ tv,
                        ushort_t* __restrict__ vfh, ushort_t* __restrict__ vfl) {
    __shared__ float tile[64][65];
    int t = blockIdx.x;
    int d0 = blockIdx.y * 64;
    int tid = threadIdx.x;
    const float* src = tv + ((size_t)t << 14) + d0;
    ushort_t* dh = vfh + ((size_t)t << 14);
    ushort_t* dl = vfl + ((size_t)t << 14);
#pragma unroll
    for (int r = 0; r < 16; ++r) {
        int idx = r * 256 + tid;
        int s = idx >> 6, d = idx & 63;
        tile[s][d] = src[s * D_N + d];
    }
    __syncthreads();
#pragma unroll
    for (int r = 0; r < 16; ++r) {
        int idx = r * 256 + tid;
        int d = idx >> 6, s = idx & 63;
        int dg = d0 + d;
        float x = tile[s][d];
        ushort_t h, l;
        split_bf16(x, h, l);
        int w = dg >> 5, ni = (dg >> 4) & 1, lrd = dg & 15;
        int k0g = s >> 5, lk = (s >> 3) & 3, e = s & 7;
        size_t off = (size_t)(w << 11) + (k0g << 10) + (ni << 9) + lk * 128 + lrd * 8 + e;
        dh[off] = h;
        dl[off] = l;
    }
}

// ---------- prep: permuted img_value for vectorized epilogue (8-wave layout) ----------
// vP[i][w8][lr16][q64][ni2] = vimg[i][q][w*32 + ni*16 + lr]   (0 for q>=49)
__global__ void prep_vp(const float* __restrict__ vimg, float* __restrict__ vP) {
    int i = blockIdx.x;
    int tid = threadIdx.x;
    const float* src = vimg + (size_t)i * Q_N * D_N;
    float* dst = vP + ((size_t)i << 14);
#pragma unroll
    for (int r = 0; r < 64; ++r) {
        int o = r * 256 + tid;
        int ni = o & 1;
        int q = (o >> 1) & 63;
        int lr = (o >> 7) & 15;
        int w = o >> 11;
        int d = w * 32 + ni * 16 + lr;
        dst[o] = (q < Q_N) ? src[q * D_N + d] : 0.0f;
    }
}

// ---------- main: one 512-thread block per (t,i) ----------
__launch_bounds__(512, 4)
__global__ void i2t_mfma(const ushort_t* __restrict__ khs, const ushort_t* __restrict__ kls,
                         const ushort_t* __restrict__ qfh, const ushort_t* __restrict__ qfl,
                         const ushort_t* __restrict__ vfh, const ushort_t* __restrict__ vfl,
                         const float* __restrict__ vP,
                         const float* __restrict__ vnorm,
                         const int* __restrict__ tlen,
                         float* __restrict__ out)
{
    // 64KB region: phase1 = K hi(32K)+lo(32K); after phase1 overlaid with
    // As fp32 [64][65] @0 (16640B), Ph @20480 (8K), Pl @28672 (8K).
    __shared__ __align__(16) unsigned char RK[65536];
    __shared__ float wsq[8][64], wdv[8][64];
    __shared__ float rinv[64];

    const int bid = blockIdx.x;
    const int xcd = bid & 7;
    const int j = bid >> 3;
    const int t = (xcd << 3) | (j & 7);   // each XCD owns 8 t values -> K/Vf L2-resident
    const int i = j >> 3;

    const int tid = threadIdx.x;
    const int lane = tid & 63;
    const int w = tid >> 6;        // wave 0..7
    const int lr = lane & 15;
    const int lk = lane >> 4;

    // ---- stage K (pre-swizzled global -> linear LDS copy) ----
    {
        const char* gH = (const char*)(khs + ((size_t)t << 14));
        const char* gL = (const char*)(kls + ((size_t)t << 14));
#pragma unroll
        for (int r = 0; r < 4; ++r) {
            int off = w * 4096 + r * 1024;            // wave-uniform
            gload16(gH + off + lane * 16, RK + off);
            gload16(gL + off + lane * 16, RK + 32768 + off);
        }
    }
    __syncthreads();

    // ================= Phase 1: attn[s][q] = K.Q^T, wave = 32s x 16q =================
    const int wsr = (w >> 2) * 32;    // s-base
    const int wq  = (w & 3) * 16;     // q-base
    f32x4 acc[2];
    acc[0] = (f32x4){0.f, 0.f, 0.f, 0.f};
    acc[1] = (f32x4){0.f, 0.f, 0.f, 0.f};
    {
        const ushort_t* qH = qfh + ((size_t)i << 14) + ((size_t)(w & 3) << 12);
        const ushort_t* qL = qfl + ((size_t)i << 14) + ((size_t)(w & 3) << 12);
        const ushort_t* KH = (const ushort_t*)RK;
        const ushort_t* KL = (const ushort_t*)(RK + 32768);
#pragma unroll
        for (int k8 = 0; k8 < 8; ++k8) {
            const int c = k8 * 4 + lk;               // 16B chunk index in K row
            short8 aH[2], aL[2];
#pragma unroll
            for (int mi = 0; mi < 2; ++mi) {
                int s = wsr + mi * 16 + lr;
                int o = s * 256 + ((c ^ (s & 7)) << 3);
                aH[mi] = *(const short8*)(KH + o);
                aL[mi] = *(const short8*)(KL + o);
            }
            // coalesced fragment-major Q loads: lane*16B contiguous
            short8 bH = *(const short8*)(qH + (k8 << 9) + (lane << 3));
            short8 bL = *(const short8*)(qL + (k8 << 9) + (lane << 3));
#pragma unroll
            for (int mi = 0; mi < 2; ++mi) {
                acc[mi] = __builtin_amdgcn_mfma_f32_16x16x32_bf16(aH[mi], bH, acc[mi], 0, 0, 0);
                acc[mi] = __builtin_amdgcn_mfma_f32_16x16x32_bf16(aH[mi], bL, acc[mi], 0, 0, 0);
                acc[mi] = __builtin_amdgcn_mfma_f32_16x16x32_bf16(aL[mi], bH, acc[mi], 0, 0, 0);
            }
        }
    }
    __syncthreads();    // all K LDS reads done -> region reusable

    // LeakyReLU + As overlay (K region dead)
    {
        float* As = (float*)RK;
#pragma unroll
        for (int mi = 0; mi < 2; ++mi)
#pragma unroll
            for (int r = 0; r < 4; ++r) {
                int s = wsr + mi * 16 + lk * 4 + r;
                int q = wq + lr;
                float v = acc[mi][r];
                v = (v > 0.0f) ? v : 0.1f * v;
                As[s * 65 + q] = v;
            }
    }
    __syncthreads();

    // ================= Phase 2a: per-s l2norm over q (512 threads) =================
    {
        const float* As = (const float*)RK;
        int s = tid >> 3, part = tid & 7;
        float ss = 0.0f;
#pragma unroll
        for (int q0 = 0; q0 < 64; q0 += 8) {
            float v = As[s * 65 + q0 + part];
            ss += v * v;
        }
        ss += __shfl_xor(ss, 1);
        ss += __shfl_xor(ss, 2);
        ss += __shfl_xor(ss, 4);
        if (part == 0) rinv[s] = 1.0f / fmaxf(sqrtf(ss), 1e-12f);
    }
    __syncthreads();

    // ================= Phase 2b: masked softmax + focal, write swizzled P ==========
    const int len = tlen[t];
    {
        const float* As = (const float*)RK;
        ushort_t* Ph = (ushort_t*)(RK + 20480);
        ushort_t* Pl = (ushort_t*)(RK + 28672);
        const float thr = 1.0f / (float)len;
        int q = tid >> 3, part = tid & 7;      // part handles s in [part*8, part*8+8)
        float logit[8];
        float m = -INFINITY;
#pragma unroll
        for (int k = 0; k < 8; ++k) {
            int s = part * 8 + k;
            float lg = (s < len) ? 10.0f * As[s * 65 + q] * rinv[s] : -INFINITY;
            logit[k] = lg;
            m = fmaxf(m, lg);
        }
        m = fmaxf(m, __shfl_xor(m, 1));
        m = fmaxf(m, __shfl_xor(m, 2));
        m = fmaxf(m, __shfl_xor(m, 4));
        float p[8];
        float sum = 0.0f;
#pragma unroll
        for (int k = 0; k < 8; ++k) {
            int s = part * 8 + k;
            float e = (s < len) ? __expf(logit[k] - m) : 0.0f;
            p[k] = e;
            sum += e;
        }
        sum += __shfl_xor(sum, 1);
        sum += __shfl_xor(sum, 2);
        sum += __shfl_xor(sum, 4);
        float inv = 1.0f / sum;
        float sk = 0.0f;
#pragma unroll
        for (int k = 0; k < 8; ++k) {
            p[k] *= inv;
            if (p[k] > thr) sk += p[k];
        }
        sk += __shfl_xor(sk, 1);
        sk += __shfl_xor(sk, 2);
        sk += __shfl_xor(sk, 4);
        float iv2 = 1.0f / sk;

        short8 vh, vl;
#pragma unroll
        for (int k = 0; k < 8; ++k) {
            float pv = (p[k] > thr) ? p[k] * iv2 : 0.0f;
            if (q >= Q_N) pv = 0.0f;
            ushort_t hh, ll;
            split_bf16(pv, hh, ll);
            vh[k] = (short)hh;
            vl[k] = (short)ll;
        }
        int o = q * 64 + ((part ^ (q & 7)) << 3);    // ushort units, swizzled chunk
        *(short8*)(Ph + o) = vh;
        *(short8*)(Pl + o) = vl;
    }
    __syncthreads();

    // ================= Phase 3: wei[q][d] = P[q][s]*Vt[d][s]; wave = 64q x 32d ======
    f32x4 acc2[4][2];
#pragma unroll
    for (int a = 0; a < 4; ++a)
#pragma unroll
        for (int b = 0; b < 2; ++b) acc2[a][b] = (f32x4){0.f, 0.f, 0.f, 0.f};
    {
        const ushort_t* vH = vfh + ((size_t)t << 14) + (size_t)(w << 11);
        const ushort_t* vL = vfl + ((size_t)t << 14) + (size_t)(w << 11);
        const ushort_t* PH = (const ushort_t*)(RK + 20480);
        const ushort_t* PL = (const ushort_t*)(RK + 28672);
#pragma unroll
        for (int k0g = 0; k0g < 2; ++k0g) {
            short8 pah[4], pal[4];
#pragma unroll
            for (int mi = 0; mi < 4; ++mi) {
                int q = mi * 16 + lr;
                int c = k0g * 4 + lk;
                int o = q * 64 + ((c ^ (q & 7)) << 3);
                pah[mi] = *(const short8*)(PH + o);
                pal[mi] = *(const short8*)(PL + o);
            }
#pragma unroll
            for (int ni = 0; ni < 2; ++ni) {
                // coalesced fragment-major Vt loads
                short8 bh = *(const short8*)(vH + (k0g << 10) + (ni << 9) + (lane << 3));
                short8 bl = *(const short8*)(vL + (k0g << 10) + (ni << 9) + (lane << 3));
#pragma unroll
                for (int mi = 0; mi < 4; ++mi) {
                    acc2[mi][ni] = __builtin_amdgcn_mfma_f32_16x16x32_bf16(pah[mi], bh, acc2[mi][ni], 0, 0, 0);
                    acc2[mi][ni] = __builtin_amdgcn_mfma_f32_16x16x32_bf16(pal[mi], bh, acc2[mi][ni], 0, 0, 0);
                    acc2[mi][ni] = __builtin_amdgcn_mfma_f32_16x16x32_bf16(pah[mi], bl, acc2[mi][ni], 0, 0, 0);
                }
            }
        }
    }

    // ================= Epilogue: fused ||wei|| and wei.v, reduce over d =============
    {
        const float* vPb = vP + ((((size_t)i * 8 + w) * 16 + lr) << 7);
#pragma unroll
        for (int mi = 0; mi < 4; ++mi)
#pragma unroll
            for (int r = 0; r < 4; ++r) {
                int q = mi * 16 + lk * 4 + r;
                f32x2 vv = *(const f32x2*)(vPb + q * 2);
                float s2 = 0.0f, dv = 0.0f;
#pragma unroll
                for (int ni = 0; ni < 2; ++ni) {
                    float wv = acc2[mi][ni][r];
                    s2 += wv * wv;
                    dv += wv * vv[ni];
                }
#pragma unroll
                for (int mask = 1; mask <= 8; mask <<= 1) {
                    s2 += __shfl_xor(s2, mask);
                    dv += __shfl_xor(dv, mask);
                }
                if (lr == 0) { wsq[w][q] = s2; wdv[w][q] = dv; }
            }
    }
    __syncthreads();
    if (tid < 64) {
        int q = tid;
        float s2 = 0.0f, dv = 0.0f;
#pragma unroll
        for (int ww = 0; ww < 8; ++ww) { s2 += wsq[ww][q]; dv += wdv[ww][q]; }
        float sim = 0.0f;
        if (q < Q_N) {
            float wn = sqrtf(s2);
            float w12 = dv / fmaxf(wn, 1e-12f);
            float wnn = wn / fmaxf(wn, 1e-12f);
            float denom = fmaxf(vnorm[i * 64 + q] * wnn, 1e-8f);
            sim = w12 / denom;
        }
        sim = waveReduceSum64(sim);
        if (tid == 0) out[(size_t)i * T_N + t] = sim * (1.0f / (float)Q_N);
    }
}

extern "C" void kernel_launch(void* const* d_in, const int* in_sizes, int n_in,
                              void* d_out, int out_size, void* d_ws, size_t ws_size,
                              hipStream_t stream) {
    const float* img_query = (const float*)d_in[0];  // [I,49,D]
    const float* img_value = (const float*)d_in[1];  // [I,49,D]
    const float* text_key  = (const float*)d_in[2];  // [T,64,D]
    const float* text_val  = (const float*)d_in[3];  // [T,64,D]
    const int*   text_len  = (const int*)d_in[4];    // [T]
    float* out = (float*)d_out;

    const size_t NPAD = (size_t)64 * 64 * 256;       // 1,048,576 elements
    ushort_t* qfh = (ushort_t*)d_ws;
    ushort_t* qfl = qfh + NPAD;
    ushort_t* khs = qfl + NPAD;
    ushort_t* kls = khs + NPAD;
    ushort_t* vfh = kls + NPAD;
    ushort_t* vfl = vfh + NPAD;
    float* vnorm  = (float*)(vfl + NPAD);            // [I*64]
    float* vP     = vnorm + I_N * 64;                // [I][8][16][64][2] = 4 MB

    prep_img<<<I_N * 64, 256, 0, stream>>>(img_query, img_value, qfh, qfl, vnorm);
    prep_txt<<<T_N * 64, 256, 0, stream>>>(text_key, khs, kls);
    prep_vt<<<dim3(T_N, 4), 256, 0, stream>>>(text_val, vfh, vfl);
    prep_vp<<<I_N, 256, 0, stream>>>(img_value, vP);

    i2t_mfma<<<T_N * I_N, 512, 0, stream>>>(khs, kls, qfh, qfl, vfh, vfl,
                                            vP, vnorm, text_len, out);
}

// Round 6
// 149.785 us; speedup vs baseline: 1.4644x; 1.0126x over previous
//
#include <hip/hip_runtime.h>
#include <math.h>

#define I_N 64
#define Q_N 49
#define T_N 64
#define S_N 64
#define D_N 256

typedef __attribute__((ext_vector_type(8))) short short8;
typedef __attribute__((ext_vector_type(4))) float f32x4;
typedef unsigned short ushort_t;

__device__ __forceinline__ float waveReduceSum64(float v) {
    v += __shfl_xor(v, 1);
    v += __shfl_xor(v, 2);
    v += __shfl_xor(v, 4);
    v += __shfl_xor(v, 8);
    v += __shfl_xor(v, 16);
    v += __shfl_xor(v, 32);
    return v;
}

__device__ __forceinline__ ushort_t f2bf(float x) {
    unsigned u = __builtin_bit_cast(unsigned, x);
    unsigned r = (u + 0x7fffu + ((u >> 16) & 1u)) >> 16;
    return (ushort_t)r;
}
__device__ __forceinline__ float bf2f(ushort_t h) {
    unsigned u = ((unsigned)h) << 16;
    return __builtin_bit_cast(float, u);
}
__device__ __forceinline__ void split_bf16(float x, ushort_t& h, ushort_t& l) {
    h = f2bf(x);
    l = f2bf(x - bf2f(h));
}

// ---------- prep: fused normalize of img-query rows (blocks 0..4095) and text-key rows
// ---------- (blocks 4096..8191); split to bf16 hi/lo in FRAGMENT-MAJOR layout:
// Xf[hi][grp][k8][lane][e]:  row = grp*16 + (lane&15), d = k8*32 + (lane>>4)*8 + e.
// Also ||img_value|| per (i,q). block = 256.
__global__ void prep_norm(const float* __restrict__ q_in, const float* __restrict__ v_in,
                          const float* __restrict__ k_in,
                          ushort_t* __restrict__ qfh, ushort_t* __restrict__ qfl,
                          ushort_t* __restrict__ kfh, ushort_t* __restrict__ kfl,
                          float* __restrict__ vnorm) {
    int b = blockIdx.x;
    int tid = threadIdx.x;                 // d
    int isimg = (b < 4096) ? 1 : 0;
    int row = isimg ? b : (b - 4096);      // hi*64 + lo
    int hi = row >> 6, lo = row & 63;
    float x = 0.0f, vv = 0.0f;
    if (isimg) {
        if (lo < Q_N) {
            size_t base = ((size_t)hi * Q_N + lo) * D_N + tid;
            x = q_in[base];
            vv = v_in[base];
        }
    } else {
        x = k_in[(size_t)row * D_N + tid];
    }
    __shared__ float ws[8];
    float s1 = waveReduceSum64(x * x);
    float s2 = waveReduceSum64(vv * vv);
    int wv = tid >> 6, ln = tid & 63;
    if (ln == 0) { ws[wv] = s1; ws[4 + wv] = s2; }
    __syncthreads();
    float n1 = sqrtf(ws[0] + ws[1] + ws[2] + ws[3]);
    float xn = x / fmaxf(n1, 1e-12f);
    ushort_t h, l;
    split_bf16(xn, h, l);
    size_t off = ((size_t)hi << 14) + (size_t)((((lo >> 4) * 8 + (tid >> 5))) << 9)
               + (size_t)(((((tid >> 3) & 3) * 16 + (lo & 15))) << 3) + (tid & 7);
    if (isimg) {
        qfh[off] = h;
        qfl[off] = l;
        if (tid == 0) vnorm[row] = sqrtf(ws[4] + ws[5] + ws[6] + ws[7]);
    } else {
        kfh[off] = h;
        kfl[off] = l;
    }
}

// ---------- prep: text value -> FRAGMENT-MAJOR transposed layout ----------
// Vf[t][w][k0g][md][lane][e]: d = w*32 + md*16 + (lane&15), s = k0g*32 + (lane>>4)*8 + e.
// grid = (T_N, 4), block = 256.
__global__ void prep_vt(const float* __restrict__ tv,
                        ushort_t* __restrict__ vfh, ushort_t* __restrict__ vfl) {
    __shared__ float tile[64][65];
    int t = blockIdx.x;
    int d0 = blockIdx.y * 64;
    int tid = threadIdx.x;
    const float* src = tv + ((size_t)t << 14) + d0;
    ushort_t* dh = vfh + ((size_t)t << 14);
    ushort_t* dl = vfl + ((size_t)t << 14);
#pragma unroll
    for (int r = 0; r < 16; ++r) {
        int idx = r * 256 + tid;
        int s = idx >> 6, d = idx & 63;
        tile[s][d] = src[s * D_N + d];
    }
    __syncthreads();
#pragma unroll
    for (int r = 0; r < 16; ++r) {
        int idx = r * 256 + tid;
        int d = idx >> 6, s = idx & 63;
        int dg = d0 + d;
        float x = tile[s][d];
        ushort_t h, l;
        split_bf16(x, h, l);
        int w = dg >> 5, md = (dg >> 4) & 1, lrd = dg & 15;
        int k0g = s >> 5, lk = (s >> 3) & 3, e = s & 7;
        size_t off = (size_t)(w << 11) + (k0g << 10) + (md << 9) + lk * 128 + lrd * 8 + e;
        dh[off] = h;
        dl[off] = l;
    }
}

// ---------- prep: permuted img_value for swapped-operand epilogue ----------
// vP[i][w8][lane64][nq4][md2][r4] = vimg[i][q=nq*16+(lane&15)][d=w*32+md*16+(lane>>4)*4+r]
__global__ void prep_vp(const float* __restrict__ vimg, float* __restrict__ vP) {
    int i = blockIdx.x;
    int tid = threadIdx.x;
    const float* src = vimg + (size_t)i * Q_N * D_N;
    float* dst = vP + ((size_t)i << 14);
#pragma unroll
    for (int rep = 0; rep < 2; ++rep) {
        int p = rep * 256 + tid;           // (w,lane)
        int w = p >> 6, lane = p & 63;
        int lr = lane & 15, lk = lane >> 4;
        float* d0 = dst + (size_t)p * 32;
#pragma unroll
        for (int nq = 0; nq < 4; ++nq) {
            int q = nq * 16 + lr;
#pragma unroll
            for (int md = 0; md < 2; ++md)
#pragma unroll
                for (int r = 0; r < 4; ++r) {
                    int d = w * 32 + md * 16 + lk * 4 + r;
                    d0[nq * 8 + md * 4 + r] = (q < Q_N) ? src[q * D_N + d] : 0.0f;
                }
        }
    }
}

// ---------- main: one 512-thread block per (t,i); 33.3KB LDS -> 4 blocks/CU ----------
__launch_bounds__(512, 8)
__global__ void i2t_mfma(const ushort_t* __restrict__ kfh, const ushort_t* __restrict__ kfl,
                         const ushort_t* __restrict__ qfh, const ushort_t* __restrict__ qfl,
                         const ushort_t* __restrict__ vfh, const ushort_t* __restrict__ vfl,
                         const float* __restrict__ vP,
                         const float* __restrict__ vnorm,
                         const int* __restrict__ tlen,
                         float* __restrict__ out)
{
    // As fp32 [64][65] @0 (16640) | rinv @16640 (256) | Ph @16896 (8K) | Pl @25088 (8K)
    // epilogue overlay on As region: wsq @0 (2K), wdv @2048 (2K)
    __shared__ __align__(16) unsigned char RK[33280];

    const int bid = blockIdx.x;
    const int xcd = bid & 7;
    const int j = bid >> 3;
    const int t = (xcd << 3) | (j & 7);   // each XCD owns 8 t values -> K/Vf L2-resident
    const int i = j >> 3;

    const int tid = threadIdx.x;
    const int lane = tid & 63;
    const int w = tid >> 6;        // wave 0..7
    const int lr = lane & 15;
    const int lk = lane >> 4;

    // ================= Phase 1: attn[s][q] = K.Q^T, wave = 32s x 16q, all global ======
    const int wsr = (w >> 2) * 32;    // s-base
    const int wq  = (w & 3) * 16;     // q-base
    f32x4 acc[2];
    acc[0] = (f32x4){0.f, 0.f, 0.f, 0.f};
    acc[1] = (f32x4){0.f, 0.f, 0.f, 0.f};
    {
        const ushort_t* kH = kfh + ((size_t)t << 14) + (size_t)(w >> 2) * 8192;
        const ushort_t* kL = kfl + ((size_t)t << 14) + (size_t)(w >> 2) * 8192;
        const ushort_t* qH = qfh + ((size_t)i << 14) + (size_t)(w & 3) * 4096;
        const ushort_t* qL = qfl + ((size_t)i << 14) + (size_t)(w & 3) * 4096;
#pragma unroll
        for (int k8 = 0; k8 < 8; ++k8) {
            int fo = k8 * 512 + lane * 8;
            short8 aH0 = *(const short8*)(kH + fo);
            short8 aL0 = *(const short8*)(kL + fo);
            short8 aH1 = *(const short8*)(kH + 4096 + fo);
            short8 aL1 = *(const short8*)(kL + 4096 + fo);
            short8 bH  = *(const short8*)(qH + fo);
            short8 bL  = *(const short8*)(qL + fo);
            acc[0] = __builtin_amdgcn_mfma_f32_16x16x32_bf16(aH0, bH, acc[0], 0, 0, 0);
            acc[0] = __builtin_amdgcn_mfma_f32_16x16x32_bf16(aH0, bL, acc[0], 0, 0, 0);
            acc[0] = __builtin_amdgcn_mfma_f32_16x16x32_bf16(aL0, bH, acc[0], 0, 0, 0);
            acc[1] = __builtin_amdgcn_mfma_f32_16x16x32_bf16(aH1, bH, acc[1], 0, 0, 0);
            acc[1] = __builtin_amdgcn_mfma_f32_16x16x32_bf16(aH1, bL, acc[1], 0, 0, 0);
            acc[1] = __builtin_amdgcn_mfma_f32_16x16x32_bf16(aL1, bH, acc[1], 0, 0, 0);
        }
    }
    // LeakyReLU + As write
    {
        float* As = (float*)RK;
#pragma unroll
        for (int mi = 0; mi < 2; ++mi)
#pragma unroll
            for (int r = 0; r < 4; ++r) {
                int s = wsr + mi * 16 + lk * 4 + r;
                int q = wq + lr;
                float v = acc[mi][r];
                v = (v > 0.0f) ? v : 0.1f * v;
                As[s * 65 + q] = v;
            }
    }
    __syncthreads();

    // ================= Phase 2a: per-s l2norm over q (512 threads) =================
    {
        const float* As = (const float*)RK;
        float* rinv = (float*)(RK + 16640);
        int s = tid >> 3, part = tid & 7;
        float ss = 0.0f;
#pragma unroll
        for (int q0 = 0; q0 < 64; q0 += 8) {
            float v = As[s * 65 + q0 + part];
            ss += v * v;
        }
        ss += __shfl_xor(ss, 1);
        ss += __shfl_xor(ss, 2);
        ss += __shfl_xor(ss, 4);
        if (part == 0) rinv[s] = 1.0f / fmaxf(sqrtf(ss), 1e-12f);
    }
    __syncthreads();

    // ================= Phase 2b: masked softmax + focal, write swizzled P ==========
    const int len = tlen[t];
    {
        const float* As = (const float*)RK;
        const float* rinv = (const float*)(RK + 16640);
        ushort_t* Ph = (ushort_t*)(RK + 16896);
        ushort_t* Pl = (ushort_t*)(RK + 25088);
        const float thr = 1.0f / (float)len;
        int q = tid >> 3, part = tid & 7;      // part handles s in [part*8, part*8+8)
        float logit[8];
        float m = -INFINITY;
#pragma unroll
        for (int k = 0; k < 8; ++k) {
            int s = part * 8 + k;
            float lg = (s < len) ? 10.0f * As[s * 65 + q] * rinv[s] : -INFINITY;
            logit[k] = lg;
            m = fmaxf(m, lg);
        }
        m = fmaxf(m, __shfl_xor(m, 1));
        m = fmaxf(m, __shfl_xor(m, 2));
        m = fmaxf(m, __shfl_xor(m, 4));
        float p[8];
        float sum = 0.0f;
#pragma unroll
        for (int k = 0; k < 8; ++k) {
            int s = part * 8 + k;
            float e = (s < len) ? __expf(logit[k] - m) : 0.0f;
            p[k] = e;
            sum += e;
        }
        sum += __shfl_xor(sum, 1);
        sum += __shfl_xor(sum, 2);
        sum += __shfl_xor(sum, 4);
        float inv = 1.0f / sum;
        float sk = 0.0f;
#pragma unroll
        for (int k = 0; k < 8; ++k) {
            p[k] *= inv;
            if (p[k] > thr) sk += p[k];
        }
        sk += __shfl_xor(sk, 1);
        sk += __shfl_xor(sk, 2);
        sk += __shfl_xor(sk, 4);
        float iv2 = 1.0f / sk;

        short8 vh, vl;
#pragma unroll
        for (int k = 0; k < 8; ++k) {
            float pv = (p[k] > thr) ? p[k] * iv2 : 0.0f;
            if (q >= Q_N) pv = 0.0f;
            ushort_t hh, ll;
            split_bf16(pv, hh, ll);
            vh[k] = (short)hh;
            vl[k] = (short)ll;
        }
        int o = q * 64 + ((part ^ (q & 7)) << 3);    // ushort units, swizzled chunk
        *(short8*)(Ph + o) = vh;
        *(short8*)(Pl + o) = vl;
    }
    __syncthreads();

    // ============ Phase 3 (swapped operands): weiT[d][q] = Vt(d,s) x P(q,s) ============
    // acc2[nq][md]: C row = d = md*16 + lk*4 + r, col = q = nq*16 + lr
    f32x4 acc2[4][2];
#pragma unroll
    for (int a = 0; a < 4; ++a)
#pragma unroll
        for (int b = 0; b < 2; ++b) acc2[a][b] = (f32x4){0.f, 0.f, 0.f, 0.f};
    {
        const ushort_t* vH = vfh + ((size_t)t << 14) + (size_t)w * 2048;
        const ushort_t* vL = vfl + ((size_t)t << 14) + (size_t)w * 2048;
        const ushort_t* PH = (const ushort_t*)(RK + 16896);
        const ushort_t* PL = (const ushort_t*)(RK + 25088);
#pragma unroll
        for (int k0g = 0; k0g < 2; ++k0g) {
#pragma unroll
            for (int md = 0; md < 2; ++md) {
                int vo = k0g * 1024 + md * 512 + lane * 8;
                short8 vh = *(const short8*)(vH + vo);
                short8 vl = *(const short8*)(vL + vo);
#pragma unroll
                for (int nq = 0; nq < 4; ++nq) {
                    int q = nq * 16 + lr;
                    int o = q * 64 + (((k0g * 4 + lk) ^ (q & 7)) << 3);
                    short8 ph = *(const short8*)(PH + o);
                    short8 pl = *(const short8*)(PL + o);
                    acc2[nq][md] = __builtin_amdgcn_mfma_f32_16x16x32_bf16(vh, ph, acc2[nq][md], 0, 0, 0);
                    acc2[nq][md] = __builtin_amdgcn_mfma_f32_16x16x32_bf16(vl, ph, acc2[nq][md], 0, 0, 0);
                    acc2[nq][md] = __builtin_amdgcn_mfma_f32_16x16x32_bf16(vh, pl, acc2[nq][md], 0, 0, 0);
                }
            }
        }
    }

    // ===== Epilogue: d-reduction now over regs (r) + 2 shuffles (lk) + LDS (w) =====
    {
        float* wsq = (float*)RK;
        float* wdv = (float*)(RK + 2048);
        const float* vPb = vP + ((((size_t)i * 8 + w) * 64 + lane) << 5);
#pragma unroll
        for (int nq = 0; nq < 4; ++nq) {
            f32x4 v0 = *(const f32x4*)(vPb + nq * 8);
            f32x4 v1 = *(const f32x4*)(vPb + nq * 8 + 4);
            float s2 = 0.0f, dv = 0.0f;
#pragma unroll
            for (int r = 0; r < 4; ++r) {
                float w0 = acc2[nq][0][r];
                float w1 = acc2[nq][1][r];
                s2 += w0 * w0 + w1 * w1;
                dv += w0 * v0[r] + w1 * v1[r];
            }
            s2 += __shfl_xor(s2, 16);
            s2 += __shfl_xor(s2, 32);
            dv += __shfl_xor(dv, 16);
            dv += __shfl_xor(dv, 32);
            if (lane < 16) {
                wsq[w * 64 + nq * 16 + lane] = s2;
                wdv[w * 64 + nq * 16 + lane] = dv;
            }
        }
    }
    __syncthreads();
    if (tid < 64) {
        const float* wsq = (const float*)RK;
        const float* wdv = (const float*)(RK + 2048);
        int q = tid;
        float s2 = 0.0f, dv = 0.0f;
#pragma unroll
        for (int ww = 0; ww < 8; ++ww) {
            s2 += wsq[ww * 64 + q];
            dv += wdv[ww * 64 + q];
        }
        float sim = 0.0f;
        if (q < Q_N) {
            float wn = sqrtf(s2);
            float w12 = dv / fmaxf(wn, 1e-12f);
            float wnn = wn / fmaxf(wn, 1e-12f);
            float denom = fmaxf(vnorm[i * 64 + q] * wnn, 1e-8f);
            sim = w12 / denom;
        }
        sim = waveReduceSum64(sim);
        if (tid == 0) out[(size_t)i * T_N + t] = sim * (1.0f / (float)Q_N);
    }
}

extern "C" void kernel_launch(void* const* d_in, const int* in_sizes, int n_in,
                              void* d_out, int out_size, void* d_ws, size_t ws_size,
                              hipStream_t stream) {
    const float* img_query = (const float*)d_in[0];  // [I,49,D]
    const float* img_value = (const float*)d_in[1];  // [I,49,D]
    const float* text_key  = (const float*)d_in[2];  // [T,64,D]
    const float* text_val  = (const float*)d_in[3];  // [T,64,D]
    const int*   text_len  = (const int*)d_in[4];    // [T]
    float* out = (float*)d_out;

    const size_t NPAD = (size_t)64 * 64 * 256;       // 1,048,576 elements
    ushort_t* qfh = (ushort_t*)d_ws;
    ushort_t* qfl = qfh + NPAD;
    ushort_t* kfh = qfl + NPAD;
    ushort_t* kfl = kfh + NPAD;
    ushort_t* vfh = kfl + NPAD;
    ushort_t* vfl = vfh + NPAD;
    float* vnorm  = (float*)(vfl + NPAD);            // [I*64]
    float* vP     = vnorm + I_N * 64;                // [I][8][64][32] = 4 MB

    prep_norm<<<8192, 256, 0, stream>>>(img_query, img_value, text_key,
                                        qfh, qfl, kfh, kfl, vnorm);
    prep_vt<<<dim3(T_N, 4), 256, 0, stream>>>(text_val, vfh, vfl);
    prep_vp<<<I_N, 256, 0, stream>>>(img_value, vP);

    i2t_mfma<<<T_N * I_N, 512, 0, stream>>>(kfh, kfl, qfh, qfl, vfh, vfl,
                                            vP, vnorm, text_len, out);
}

// Round 7
// 129.092 us; speedup vs baseline: 1.6992x; 1.1603x over previous
//
#include <hip/hip_runtime.h>
#include <math.h>

#define I_N 64
#define Q_N 49
#define T_N 64
#define S_N 64
#define D_N 256

typedef __attribute__((ext_vector_type(8))) short short8;
typedef __attribute__((ext_vector_type(4))) float f32x4;
typedef unsigned short ushort_t;

__device__ __forceinline__ float waveReduceSum64(float v) {
    v += __shfl_xor(v, 1);
    v += __shfl_xor(v, 2);
    v += __shfl_xor(v, 4);
    v += __shfl_xor(v, 8);
    v += __shfl_xor(v, 16);
    v += __shfl_xor(v, 32);
    return v;
}

__device__ __forceinline__ ushort_t f2bf(float x) {
    unsigned u = __builtin_bit_cast(unsigned, x);
    unsigned r = (u + 0x7fffu + ((u >> 16) & 1u)) >> 16;
    return (ushort_t)r;
}
__device__ __forceinline__ float bf2f(ushort_t h) {
    unsigned u = ((unsigned)h) << 16;
    return __builtin_bit_cast(float, u);
}
__device__ __forceinline__ void split_bf16(float x, ushort_t& h, ushort_t& l) {
    h = f2bf(x);
    l = f2bf(x - bf2f(h));
}

// ---------- prep: fused normalize of img-query rows (blocks 0..4095) and text-key rows
// ---------- (blocks 4096..8191); split to bf16 hi/lo in FRAGMENT-MAJOR layout:
// Xf[hi][grp][k8][lane][e]:  row = grp*16 + (lane&15), d = k8*32 + (lane>>4)*8 + e.
// Also ||img_value|| per (i,q). block = 256.
__global__ void prep_norm(const float* __restrict__ q_in, const float* __restrict__ v_in,
                          const float* __restrict__ k_in,
                          ushort_t* __restrict__ qfh, ushort_t* __restrict__ qfl,
                          ushort_t* __restrict__ kfh, ushort_t* __restrict__ kfl,
                          float* __restrict__ vnorm) {
    int b = blockIdx.x;
    int tid = threadIdx.x;                 // d
    int isimg = (b < 4096) ? 1 : 0;
    int row = isimg ? b : (b - 4096);      // hi*64 + lo
    int hi = row >> 6, lo = row & 63;
    float x = 0.0f, vv = 0.0f;
    if (isimg) {
        if (lo < Q_N) {
            size_t base = ((size_t)hi * Q_N + lo) * D_N + tid;
            x = q_in[base];
            vv = v_in[base];
        }
    } else {
        x = k_in[(size_t)row * D_N + tid];
    }
    __shared__ float ws[8];
    float s1 = waveReduceSum64(x * x);
    float s2 = waveReduceSum64(vv * vv);
    int wv = tid >> 6, ln = tid & 63;
    if (ln == 0) { ws[wv] = s1; ws[4 + wv] = s2; }
    __syncthreads();
    float n1 = sqrtf(ws[0] + ws[1] + ws[2] + ws[3]);
    float xn = x / fmaxf(n1, 1e-12f);
    ushort_t h, l;
    split_bf16(xn, h, l);
    size_t off = ((size_t)hi << 14) + (size_t)((((lo >> 4) * 8 + (tid >> 5))) << 9)
               + (size_t)(((((tid >> 3) & 3) * 16 + (lo & 15))) << 3) + (tid & 7);
    if (isimg) {
        qfh[off] = h;
        qfl[off] = l;
        if (tid == 0) vnorm[row] = sqrtf(ws[4] + ws[5] + ws[6] + ws[7]);
    } else {
        kfh[off] = h;
        kfl[off] = l;
    }
}

// ---------- prep: text value -> FRAGMENT-MAJOR transposed layout ----------
// Vf[t][w][k0g][md][lane][e]: d = w*32 + md*16 + (lane&15), s = k0g*32 + (lane>>4)*8 + e.
// grid = (T_N, 4), block = 256.
__global__ void prep_vt(const float* __restrict__ tv,
                        ushort_t* __restrict__ vfh, ushort_t* __restrict__ vfl) {
    __shared__ float tile[64][65];
    int t = blockIdx.x;
    int d0 = blockIdx.y * 64;
    int tid = threadIdx.x;
    const float* src = tv + ((size_t)t << 14) + d0;
    ushort_t* dh = vfh + ((size_t)t << 14);
    ushort_t* dl = vfl + ((size_t)t << 14);
#pragma unroll
    for (int r = 0; r < 16; ++r) {
        int idx = r * 256 + tid;
        int s = idx >> 6, d = idx & 63;
        tile[s][d] = src[s * D_N + d];
    }
    __syncthreads();
#pragma unroll
    for (int r = 0; r < 16; ++r) {
        int idx = r * 256 + tid;
        int d = idx >> 6, s = idx & 63;
        int dg = d0 + d;
        float x = tile[s][d];
        ushort_t h, l;
        split_bf16(x, h, l);
        int w = dg >> 5, md = (dg >> 4) & 1, lrd = dg & 15;
        int k0g = s >> 5, lk = (s >> 3) & 3, e = s & 7;
        size_t off = (size_t)(w << 11) + (k0g << 10) + (md << 9) + lk * 128 + lrd * 8 + e;
        dh[off] = h;
        dl[off] = l;
    }
}

// ---------- prep: permuted img_value for swapped-operand epilogue ----------
// vP[i][w8][lane64][nq4][md2][r4] = vimg[i][q=nq*16+(lane&15)][d=w*32+md*16+(lane>>4)*4+r]
__global__ void prep_vp(const float* __restrict__ vimg, float* __restrict__ vP) {
    int i = blockIdx.x;
    int tid = threadIdx.x;
    const float* src = vimg + (size_t)i * Q_N * D_N;
    float* dst = vP + ((size_t)i << 14);
#pragma unroll
    for (int rep = 0; rep < 2; ++rep) {
        int p = rep * 256 + tid;           // (w,lane)
        int w = p >> 6, lane = p & 63;
        int lr = lane & 15, lk = lane >> 4;
        float* d0 = dst + (size_t)p * 32;
#pragma unroll
        for (int nq = 0; nq < 4; ++nq) {
            int q = nq * 16 + lr;
#pragma unroll
            for (int md = 0; md < 2; ++md)
#pragma unroll
                for (int r = 0; r < 4; ++r) {
                    int d = w * 32 + md * 16 + lk * 4 + r;
                    d0[nq * 8 + md * 4 + r] = (q < Q_N) ? src[q * D_N + d] : 0.0f;
                }
        }
    }
}

// ---------- main: one 512-thread block per (t,i); 33.3KB LDS, 3 blocks/CU ----------
__launch_bounds__(512, 6)
__global__ void i2t_mfma(const ushort_t* __restrict__ kfh, const ushort_t* __restrict__ kfl,
                         const ushort_t* __restrict__ qfh, const ushort_t* __restrict__ qfl,
                         const ushort_t* __restrict__ vfh, const ushort_t* __restrict__ vfl,
                         const float* __restrict__ vP,
                         const float* __restrict__ vnorm,
                         const int* __restrict__ tlen,
                         float* __restrict__ out)
{
    // As fp32 [64][65] @0 (16640) | rinv @16640 (256) | Ph @16896 (8K) | Pl @25088 (8K)
    // epilogue overlay on As region: wsq @0 (2K), wdv @2048 (2K)
    __shared__ __align__(16) unsigned char RK[33280];

    const int bid = blockIdx.x;
    const int xcd = bid & 7;
    const int j = bid >> 3;
    const int t = (xcd << 3) | (j & 7);   // each XCD owns 8 t values -> K/Vf L2-resident
    const int i = j >> 3;

    const int tid = threadIdx.x;
    const int lane = tid & 63;
    const int w = tid >> 6;        // wave 0..7
    const int lr = lane & 15;
    const int lk = lane >> 4;

    // ================= Phase 1: attn[s][q] = K.Q^T, wave = 32s x 16q, all global ======
    const int wsr = (w >> 2) * 32;    // s-base
    const int wq  = (w & 3) * 16;     // q-base
    f32x4 acc[2];
    acc[0] = (f32x4){0.f, 0.f, 0.f, 0.f};
    acc[1] = (f32x4){0.f, 0.f, 0.f, 0.f};
    {
        const ushort_t* kH = kfh + ((size_t)t << 14) + (size_t)(w >> 2) * 8192;
        const ushort_t* kL = kfl + ((size_t)t << 14) + (size_t)(w >> 2) * 8192;
        const ushort_t* qH = qfh + ((size_t)i << 14) + (size_t)(w & 3) * 4096;
        const ushort_t* qL = qfl + ((size_t)i << 14) + (size_t)(w & 3) * 4096;
#pragma unroll
        for (int k8 = 0; k8 < 8; ++k8) {
            int fo = k8 * 512 + lane * 8;
            short8 aH0 = *(const short8*)(kH + fo);
            short8 aL0 = *(const short8*)(kL + fo);
            short8 aH1 = *(const short8*)(kH + 4096 + fo);
            short8 aL1 = *(const short8*)(kL + 4096 + fo);
            short8 bH  = *(const short8*)(qH + fo);
            short8 bL  = *(const short8*)(qL + fo);
            acc[0] = __builtin_amdgcn_mfma_f32_16x16x32_bf16(aH0, bH, acc[0], 0, 0, 0);
            acc[0] = __builtin_amdgcn_mfma_f32_16x16x32_bf16(aH0, bL, acc[0], 0, 0, 0);
            acc[0] = __builtin_amdgcn_mfma_f32_16x16x32_bf16(aL0, bH, acc[0], 0, 0, 0);
            acc[1] = __builtin_amdgcn_mfma_f32_16x16x32_bf16(aH1, bH, acc[1], 0, 0, 0);
            acc[1] = __builtin_amdgcn_mfma_f32_16x16x32_bf16(aH1, bL, acc[1], 0, 0, 0);
            acc[1] = __builtin_amdgcn_mfma_f32_16x16x32_bf16(aL1, bH, acc[1], 0, 0, 0);
        }
    }
    // LeakyReLU + As write
    {
        float* As = (float*)RK;
#pragma unroll
        for (int mi = 0; mi < 2; ++mi)
#pragma unroll
            for (int r = 0; r < 4; ++r) {
                int s = wsr + mi * 16 + lk * 4 + r;
                int q = wq + lr;
                float v = acc[mi][r];
                v = (v > 0.0f) ? v : 0.1f * v;
                As[s * 65 + q] = v;
            }
    }
    __syncthreads();

    // ================= Phase 2a: per-s l2norm over q (512 threads) =================
    {
        const float* As = (const float*)RK;
        float* rinv = (float*)(RK + 16640);
        int s = tid >> 3, part = tid & 7;
        float ss = 0.0f;
#pragma unroll
        for (int q0 = 0; q0 < 64; q0 += 8) {
            float v = As[s * 65 + q0 + part];
            ss += v * v;
        }
        ss += __shfl_xor(ss, 1);
        ss += __shfl_xor(ss, 2);
        ss += __shfl_xor(ss, 4);
        if (part == 0) rinv[s] = 1.0f / fmaxf(sqrtf(ss), 1e-12f);
    }
    __syncthreads();

    // ================= Phase 2b: masked softmax + focal, write swizzled P ==========
    const int len = tlen[t];
    {
        const float* As = (const float*)RK;
        const float* rinv = (const float*)(RK + 16640);
        ushort_t* Ph = (ushort_t*)(RK + 16896);
        ushort_t* Pl = (ushort_t*)(RK + 25088);
        const float thr = 1.0f / (float)len;
        int q = tid >> 3, part = tid & 7;      // part handles s in [part*8, part*8+8)
        float logit[8];
        float m = -INFINITY;
#pragma unroll
        for (int k = 0; k < 8; ++k) {
            int s = part * 8 + k;
            float lg = (s < len) ? 10.0f * As[s * 65 + q] * rinv[s] : -INFINITY;
            logit[k] = lg;
            m = fmaxf(m, lg);
        }
        m = fmaxf(m, __shfl_xor(m, 1));
        m = fmaxf(m, __shfl_xor(m, 2));
        m = fmaxf(m, __shfl_xor(m, 4));
        float p[8];
        float sum = 0.0f;
#pragma unroll
        for (int k = 0; k < 8; ++k) {
            int s = part * 8 + k;
            float e = (s < len) ? __expf(logit[k] - m) : 0.0f;
            p[k] = e;
            sum += e;
        }
        sum += __shfl_xor(sum, 1);
        sum += __shfl_xor(sum, 2);
        sum += __shfl_xor(sum, 4);
        float inv = 1.0f / sum;
        float sk = 0.0f;
#pragma unroll
        for (int k = 0; k < 8; ++k) {
            p[k] *= inv;
            if (p[k] > thr) sk += p[k];
        }
        sk += __shfl_xor(sk, 1);
        sk += __shfl_xor(sk, 2);
        sk += __shfl_xor(sk, 4);
        float iv2 = 1.0f / sk;

        short8 vh, vl;
#pragma unroll
        for (int k = 0; k < 8; ++k) {
            float pv = (p[k] > thr) ? p[k] * iv2 : 0.0f;
            if (q >= Q_N) pv = 0.0f;
            ushort_t hh, ll;
            split_bf16(pv, hh, ll);
            vh[k] = (short)hh;
            vl[k] = (short)ll;
        }
        int o = q * 64 + ((part ^ (q & 7)) << 3);    // ushort units, swizzled chunk
        *(short8*)(Ph + o) = vh;
        *(short8*)(Pl + o) = vl;
    }
    __syncthreads();

    // ============ Phase 3 (swapped operands): weiT[d][q] = Vt(d,s) x P(q,s) ============
    // acc2[nq][md]: C row = d = md*16 + lk*4 + r, col = q = nq*16 + lr
    f32x4 acc2[4][2];
#pragma unroll
    for (int a = 0; a < 4; ++a)
#pragma unroll
        for (int b = 0; b < 2; ++b) acc2[a][b] = (f32x4){0.f, 0.f, 0.f, 0.f};
    {
        const ushort_t* vH = vfh + ((size_t)t << 14) + (size_t)w * 2048;
        const ushort_t* vL = vfl + ((size_t)t << 14) + (size_t)w * 2048;
        const ushort_t* PH = (const ushort_t*)(RK + 16896);
        const ushort_t* PL = (const ushort_t*)(RK + 25088);
#pragma unroll
        for (int k0g = 0; k0g < 2; ++k0g) {
#pragma unroll
            for (int md = 0; md < 2; ++md) {
                int vo = k0g * 1024 + md * 512 + lane * 8;
                short8 vh = *(const short8*)(vH + vo);
                short8 vl = *(const short8*)(vL + vo);
#pragma unroll
                for (int nq = 0; nq < 4; ++nq) {
                    int q = nq * 16 + lr;
                    int o = q * 64 + (((k0g * 4 + lk) ^ (q & 7)) << 3);
                    short8 ph = *(const short8*)(PH + o);
                    short8 pl = *(const short8*)(PL + o);
                    acc2[nq][md] = __builtin_amdgcn_mfma_f32_16x16x32_bf16(vh, ph, acc2[nq][md], 0, 0, 0);
                    acc2[nq][md] = __builtin_amdgcn_mfma_f32_16x16x32_bf16(vl, ph, acc2[nq][md], 0, 0, 0);
                    acc2[nq][md] = __builtin_amdgcn_mfma_f32_16x16x32_bf16(vh, pl, acc2[nq][md], 0, 0, 0);
                }
            }
        }
    }

    // ===== Epilogue: d-reduction over regs (r) + 2 shuffles (lk) + LDS (w) =====
    {
        float* wsq = (float*)RK;
        float* wdv = (float*)(RK + 2048);
        const float* vPb = vP + ((((size_t)i * 8 + w) * 64 + lane) << 5);
#pragma unroll
        for (int nq = 0; nq < 4; ++nq) {
            f32x4 v0 = *(const f32x4*)(vPb + nq * 8);
            f32x4 v1 = *(const f32x4*)(vPb + nq * 8 + 4);
            float s2 = 0.0f, dv = 0.0f;
#pragma unroll
            for (int r = 0; r < 4; ++r) {
                float w0 = acc2[nq][0][r];
                float w1 = acc2[nq][1][r];
                s2 += w0 * w0 + w1 * w1;
                dv += w0 * v0[r] + w1 * v1[r];
            }
            s2 += __shfl_xor(s2, 16);
            s2 += __shfl_xor(s2, 32);
            dv += __shfl_xor(dv, 16);
            dv += __shfl_xor(dv, 32);
            if (lane < 16) {
                wsq[w * 64 + nq * 16 + lane] = s2;
                wdv[w * 64 + nq * 16 + lane] = dv;
            }
        }
    }
    __syncthreads();
    if (tid < 64) {
        const float* wsq = (const float*)RK;
        const float* wdv = (const float*)(RK + 2048);
        int q = tid;
        float s2 = 0.0f, dv = 0.0f;
#pragma unroll
        for (int ww = 0; ww < 8; ++ww) {
            s2 += wsq[ww * 64 + q];
            dv += wdv[ww * 64 + q];
        }
        float sim = 0.0f;
        if (q < Q_N) {
            float wn = sqrtf(s2);
            float w12 = dv / fmaxf(wn, 1e-12f);
            float wnn = wn / fmaxf(wn, 1e-12f);
            float denom = fmaxf(vnorm[i * 64 + q] * wnn, 1e-8f);
            sim = w12 / denom;
        }
        sim = waveReduceSum64(sim);
        if (tid == 0) out[(size_t)i * T_N + t] = sim * (1.0f / (float)Q_N);
    }
}

extern "C" void kernel_launch(void* const* d_in, const int* in_sizes, int n_in,
                              void* d_out, int out_size, void* d_ws, size_t ws_size,
                              hipStream_t stream) {
    const float* img_query = (const float*)d_in[0];  // [I,49,D]
    const float* img_value = (const float*)d_in[1];  // [I,49,D]
    const float* text_key  = (const float*)d_in[2];  // [T,64,D]
    const float* text_val  = (const float*)d_in[3];  // [T,64,D]
    const int*   text_len  = (const int*)d_in[4];    // [T]
    float* out = (float*)d_out;

    const size_t NPAD = (size_t)64 * 64 * 256;       // 1,048,576 elements
    ushort_t* qfh = (ushort_t*)d_ws;
    ushort_t* qfl = qfh + NPAD;
    ushort_t* kfh = qfl + NPAD;
    ushort_t* kfl = kfh + NPAD;
    ushort_t* vfh = kfl + NPAD;
    ushort_t* vfl = vfh + NPAD;
    float* vnorm  = (float*)(vfl + NPAD);            // [I*64]
    float* vP     = vnorm + I_N * 64;                // [I][8][64][32] = 4 MB

    prep_norm<<<8192, 256, 0, stream>>>(img_query, img_value, text_key,
                                        qfh, qfl, kfh, kfl, vnorm);
    prep_vt<<<dim3(T_N, 4), 256, 0, stream>>>(text_val, vfh, vfl);
    prep_vp<<<I_N, 256, 0, stream>>>(img_value, vP);

    i2t_mfma<<<T_N * I_N, 512, 0, stream>>>(kfh, kfl, qfh, qfl, vfh, vfl,
                                            vP, vnorm, text_len, out);
}